// Round 13
// baseline (3124.270 us; speedup 1.0000x reference)
//
#include <hip/hip_runtime.h>
#include <cmath>

static constexpr int UNITS = 1024;
static constexpr int ORDER = 256;
static constexpr int D_IN  = 256;
static constexpr int BATCH = 64;
static constexpr int SEQ   = 512;

// Swizzled plane: 40 cells x 1024B per plane (k-cells 8..47 of the extended
// [x|h|m] vector; cells 0..7 are x, kept local). Cell c (c>=8) holds elems
// k = c*32 + lgrp*8 + e for 16 rows: byte = (c-8)*1024 + (lgrp*16+row)*16 + e*2
static constexpr int GPLANE = 40960;         // one plane (hi or lo) per group
static constexpr int GSET   = 81920;         // hi+lo per group

// ws byte layout
static constexpr size_t XE_OFF = 0;          // 64*512 f32
static constexpr size_t FG_OFF = 131072;     // 4 groups * 256 u32 (per-WAVE flags)
static constexpr size_t UP_OFF = 135168;     // 2 slots * 64 b * 80 f32
static constexpr size_t P_OFF  = 176128;     // 2 sets * PSET
static constexpr size_t PSET   = 327680;     // 4 groups * GSET
// zero region [FG_OFF, P_OFF+2*PSET) = 700416 B = 175104 words

// dynamic-LDS byte offsets (base 16B-aligned)
static constexpr int SXH_OFF  = 0;           // x hi plane [16][528B]
static constexpr int SXL_OFF  = 8448;        // x lo plane [16][528B]
static constexpr int RED_OFF  = 16896;       // 1024 f32: slot r*256 + wave*64 + lane
static constexpr int RED2_OFF = 20992;       // 1024 f32
static constexpr int ULDS_OFF = 25088;       // 16 f32
static constexpr int BVS_OFF  = 25152;       // 16 f32
static constexpr int LDS_BYTES = 25216;
// setup-only alias: WMC = [256][16] f32 = 16384 B at offset 0

typedef __attribute__((ext_vector_type(8))) short bf16x8;
typedef __attribute__((ext_vector_type(4))) float f32x4;
typedef unsigned long long u64;

__device__ __forceinline__ unsigned short bf16rn(float f) {
    unsigned u = __builtin_bit_cast(unsigned, f);
    u += 0x7FFFu + ((u >> 16) & 1u);
    return (unsigned short)(u >> 16);
}
__device__ __forceinline__ float bf2f(unsigned short h) {
    unsigned u = ((unsigned)h) << 16;
    return __builtin_bit_cast(float, u);
}

// ---- L2-bypass data path: relaxed system-scope atomics (compiler-managed,
// lower to sc0 sc1 global ops, coherence point = Infinity Cache, no fences).
__device__ __forceinline__ u64 ld_sys(const void* p) {
    return __hip_atomic_load((const u64*)p, __ATOMIC_RELAXED, __HIP_MEMORY_SCOPE_SYSTEM);
}
__device__ __forceinline__ void st_sys32(void* p, unsigned v) {
    __hip_atomic_store((unsigned*)p, v, __ATOMIC_RELAXED, __HIP_MEMORY_SCOPE_SYSTEM);
}
__device__ __forceinline__ bf16x8 mk8(u64 a, u64 b) {
    union { u64 q[2]; bf16x8 v; } u;
    u.q[0] = a; u.q[1] = b;
    return u.v;
}

__global__ __launch_bounds__(256) void lmu_pre(const float* __restrict__ x,
                                               const float* __restrict__ ie,
                                               char* __restrict__ ws) {
    int gid  = blockIdx.x * blockDim.x + threadIdx.x;
    int wave = gid >> 6;
    int lane = gid & 63;
    if (wave < BATCH * SEQ) {
        const float* row = x + (size_t)wave * D_IN;
        float s = 0.f;
        #pragma unroll
        for (int c = 0; c < D_IN; c += 64) s += row[c + lane] * ie[c + lane];
        #pragma unroll
        for (int off = 32; off > 0; off >>= 1) s += __shfl_down(s, off);
        if (lane == 0) ((float*)(ws + XE_OFF))[wave] = s;
    }
    // zero flags + both UP slots + both plane sets (contiguous region)
    if (gid < 175104) ((unsigned*)(ws + FG_OFF))[gid] = 0u;
}

__global__ __launch_bounds__(256, 1) void lmu_main(
        const float* __restrict__ x,
        const float* __restrict__ he,
        const float* __restrict__ me,
        const float* __restrict__ Wi,
        const float* __restrict__ Wh,
        const float* __restrict__ Wm,
        const float* __restrict__ AT,
        const float* __restrict__ BT,
        float* __restrict__ out,
        char* __restrict__ ws) {
    extern __shared__ char smem[];
    char*  sXH  = smem + SXH_OFF;
    char*  sXL  = smem + SXL_OFF;
    float* REDs = (float*)(smem + RED_OFF);
    float* RED2 = (float*)(smem + RED2_OFF);
    float* ULDS = (float*)(smem + ULDS_OFF);
    float* BVs  = (float*)(smem + BVS_OFF);
    float* WMC  = (float*)smem;              // setup-only alias

    const int wg = blockIdx.x, tid = threadIdx.x;
    const int wave = tid >> 6, lane = tid & 63;
    const int lrow = lane & 15, lgrp = lane >> 4;
    const int grp = wg >> 6, lid = wg & 63;
    const int b0 = grp * 16, n0 = lid * 16, nglob = n0 + lrow;
    const bool mwg = (lid < 16);
    const int mt = lid & 15;

    float* XE  = (float*)(ws + XE_OFF);
    unsigned* gf = (unsigned*)(ws + FG_OFF) + (size_t)grp * 256;
    float* UPf = (float*)(ws + UP_OFF);
    char* PB   = ws + P_OFF;

    // per-thread fragment-load byte offset within a cell
    const int lb = (lgrp * 16 + lrow) * 16;

    // per-thread constant epilogue store offsets (pair stores, even lrow lanes)
    const int rowME = lgrp * 4 + wave;                 // batch row this thread writes
    const int kH = 256 + n0 + (lrow & ~1);
    const int hswz = (kH / 32 - 8) * 1024 + (((kH % 32) / 8) * 16 + rowME) * 16
                   + (kH % 8) * 2;
    const int kM = 1280 + mt * 16 + (lrow & ~1);
    const int mswz = (kM / 32 - 8) * 1024 + (((kM % 32) / 8) * 16 + rowME) * 16
                   + (kM % 8) * 2;

    // ---------------- setup ----------------
    for (int idx = tid; idx < ORDER * 16; idx += 256)
        WMC[idx] = Wm[(size_t)(idx >> 4) * UNITS + n0 + (idx & 15)];
    __syncthreads();

    // weight fragments: [Wi; Wh; Wm'] with Wm' = (I+AT)@Wm, bf16 hi/lo.
    // Balanced cell map: wave w owns x-cells {2w,2w+1} (j=0,1) and
    // exchanged cells 8+10w .. 17+10w (j=2..11).
    bf16x8 wfhi[12], wflo[12];
    #pragma unroll
    for (int j = 0; j < 12; ++j) {
        const int cell = (j < 2) ? (2 * wave + j) : (8 + wave * 10 + (j - 2));
        const int kbase = cell * 32 + lgrp * 8;
        bf16x8 vh, vl;
        #pragma unroll
        for (int e = 0; e < 8; ++e) {
            const int k = kbase + e;
            float f;
            if (k < 256)       f = Wi[(size_t)k * UNITS + nglob];
            else if (k < 1280) f = Wh[(size_t)(k - 256) * UNITS + nglob];
            else {
                const int r = k - 1280;
                float s = WMC[r * 16 + lrow];
                const float* atr = AT + (size_t)r * ORDER;
                for (int l = 0; l < ORDER; ++l) s += atr[l] * WMC[l * 16 + lrow];
                f = s;
            }
            unsigned short hb = bf16rn(f);
            unsigned short lb2 = bf16rn(f - bf2f(hb));
            vh[e] = (short)hb; vl[e] = (short)lb2;
        }
        wfhi[j] = vh; wflo[j] = vl;
    }
    // bv[n] = sum_l BT[l] * Wm[l][n]
    {
        const int nl = tid & 15, seg = tid >> 4;
        float s = 0.f;
        for (int l = seg * 16; l < seg * 16 + 16; ++l) s += BT[l] * WMC[l * 16 + nl];
        REDs[tid] = s;
    }
    __syncthreads();
    if (tid < 16) {
        float s = 0.f;
        for (int sg = 0; sg < 16; ++sg) s += REDs[sg * 16 + tid];
        BVs[tid] = s;
    }
    // M1 = (I+AT) fragments for owner wgs
    bf16x8 m1hi[2], m1lo[2];
    float btreg = 0.f, mereg = 0.f;
    if (mwg) {
        #pragma unroll
        for (int j2 = 0; j2 < 2; ++j2) {
            const int kb = wave * 64 + j2 * 32 + lgrp * 8;
            const int c = mt * 16 + lrow;
            bf16x8 vh, vl;
            #pragma unroll
            for (int e = 0; e < 8; ++e) {
                const int r = kb + e;
                float f = AT[(size_t)r * ORDER + c] + ((r == c) ? 1.f : 0.f);
                unsigned short hb = bf16rn(f);
                unsigned short lb2 = bf16rn(f - bf2f(hb));
                vh[e] = (short)hb; vl[e] = (short)lb2;
            }
            m1hi[j2] = vh; m1lo[j2] = vl;
        }
        btreg = BT[mt * 16 + lrow];
        mereg = me[mt * 16 + lrow];
    }
    __syncthreads();
    const float bvreg = BVs[lrow];
    const float hereg = he[n0 + lrow];

    // ---------------- time loop: ONE group barrier per step ----------------
    // Per-WAVE flags: flag[lid*4+wave] = t+1 released at end of iter t (after
    // that wave's vmcnt(0) drain). Consumer polls all 256 flags >= t at top of
    // iter t. Slot safety: flags >= t  =>  every wave finished iter t-1 incl.
    // its reads of slot (t-1)&1, so epilogue@t may overwrite slot (t+1)&1.
    for (int t = 0; t < SEQ; ++t) {
        // ---- stage x_t into sX (before poll; overlaps others' flag release)
        {
            const int row = tid >> 4, cs = tid & 15;
            const float4* xr = (const float4*)(x + ((size_t)(b0 + row) * SEQ + t) * D_IN
                                               + cs * 16);
            float4 v0 = xr[0], v1 = xr[1], v2 = xr[2], v3 = xr[3];
            float fs[16] = {v0.x,v0.y,v0.z,v0.w, v1.x,v1.y,v1.z,v1.w,
                            v2.x,v2.y,v2.z,v2.w, v3.x,v3.y,v3.z,v3.w};
            unsigned* dh = (unsigned*)(sXH + row * 528 + cs * 32);
            unsigned* dl = (unsigned*)(sXL + row * 528 + cs * 32);
            #pragma unroll
            for (int q = 0; q < 8; ++q) {
                unsigned short h0 = bf16rn(fs[2*q]),   h1 = bf16rn(fs[2*q+1]);
                unsigned short l0 = bf16rn(fs[2*q]   - bf2f(h0));
                unsigned short l1 = bf16rn(fs[2*q+1] - bf2f(h1));
                dh[q] = (unsigned)h0 | ((unsigned)h1 << 16);
                dl[q] = (unsigned)l0 | ((unsigned)l1 << 16);
            }
        }

        // ---- poll: thread tid polls flag[tid] >= t (no sleep, bare RT spin)
        {
            const unsigned gen = (unsigned)t;
            const unsigned* fp = gf + tid;
            unsigned v;
            do {
                asm volatile("global_load_dword %0, %1, off sc0 sc1\n\t"
                             "s_waitcnt vmcnt(0)"
                             : "=v"(v) : "v"(fp) : "memory");
            } while (v < gen);
        }
        __syncthreads();
        __builtin_amdgcn_sched_barrier(0);

        // ---- issue all fragment loads (10 exchanged cells per wave)
        const char* GH = PB + (size_t)(t & 1) * PSET + (size_t)grp * GSET;
        const char* GL = GH + GPLANE;

        u64 ah0[10], ah1[10], al0[10], al1[10];
        #pragma unroll
        for (int j2 = 0; j2 < 10; ++j2) {
            const int off = (wave * 10 + j2) * 1024 + lb;
            ah0[j2] = ld_sys(GH + off);    ah1[j2] = ld_sys(GH + off + 8);
            al0[j2] = ld_sys(GL + off);    al1[j2] = ld_sys(GL + off + 8);
        }
        u64 mh0[2], mh1[2], ml0[2], ml1[2];
        if (mwg) {
            #pragma unroll
            for (int j2 = 0; j2 < 2; ++j2) {
                const int off = (32 + 2 * wave + j2) * 1024 + lb;
                mh0[j2] = ld_sys(GH + off);    mh1[j2] = ld_sys(GH + off + 8);
                ml0[j2] = ld_sys(GL + off);    ml1[j2] = ld_sys(GL + off + 8);
            }
        }
        u64 upv[10];
        if (wave == 0) {
            const int bl = lane >> 2, q = lane & 3;
            const char* pp = (const char*)(UPf + ((size_t)(t & 1) * 64 + b0 + bl) * 80
                                           + q * 20);
            #pragma unroll
            for (int i = 0; i < 10; ++i) upv[i] = ld_sys(pp + i * 8);
        }

        // ---- x-cell MFMAs first (local data — overlap g-load latency)
        f32x4 acc = {0.f, 0.f, 0.f, 0.f};
        #pragma unroll
        for (int j = 0; j < 2; ++j) {
            const char* xp = sXH + lrow * 528 + ((2 * wave + j) * 32 + lgrp * 8) * 2;
            bf16x8 ah = *(const bf16x8*)xp;
            bf16x8 al = *(const bf16x8*)(xp + 8448);
            acc = __builtin_amdgcn_mfma_f32_16x16x32_bf16(ah, wfhi[j], acc, 0, 0, 0);
            acc = __builtin_amdgcn_mfma_f32_16x16x32_bf16(ah, wflo[j], acc, 0, 0, 0);
            acc = __builtin_amdgcn_mfma_f32_16x16x32_bf16(al, wfhi[j], acc, 0, 0, 0);
        }
        // ---- exchanged-cell MFMAs in load order
        #pragma unroll
        for (int j2 = 0; j2 < 10; ++j2) {
            bf16x8 ah = mk8(ah0[j2], ah1[j2]);
            bf16x8 al = mk8(al0[j2], al1[j2]);
            acc = __builtin_amdgcn_mfma_f32_16x16x32_bf16(ah, wfhi[2 + j2], acc, 0, 0, 0);
            acc = __builtin_amdgcn_mfma_f32_16x16x32_bf16(ah, wflo[2 + j2], acc, 0, 0, 0);
            acc = __builtin_amdgcn_mfma_f32_16x16x32_bf16(al, wfhi[2 + j2], acc, 0, 0, 0);
        }
        // ---- m-tile MFMA (owners)
        f32x4 acc2 = {0.f, 0.f, 0.f, 0.f};
        if (mwg) {
            #pragma unroll
            for (int j2 = 0; j2 < 2; ++j2) {
                bf16x8 ah = mk8(mh0[j2], mh1[j2]);
                bf16x8 al = mk8(ml0[j2], ml1[j2]);
                acc2 = __builtin_amdgcn_mfma_f32_16x16x32_bf16(ah, m1hi[j2], acc2, 0, 0, 0);
                acc2 = __builtin_amdgcn_mfma_f32_16x16x32_bf16(ah, m1lo[j2], acc2, 0, 0, 0);
                acc2 = __builtin_amdgcn_mfma_f32_16x16x32_bf16(al, m1hi[j2], acc2, 0, 0, 0);
            }
        }

        // u[b] = XE + sum of 80 partials (wave0)
        if (wave == 0) {
            const int bl = lane >> 2, q = lane & 3;
            float s = 0.f;
            #pragma unroll
            for (int i = 0; i < 10; ++i) {
                s += __builtin_bit_cast(float, (unsigned)(upv[i] & 0xFFFFFFFFu))
                   + __builtin_bit_cast(float, (unsigned)(upv[i] >> 32));
            }
            s += __shfl_xor(s, 1, 64);
            s += __shfl_xor(s, 2, 64);
            if (q == 0) ULDS[bl] = XE[(size_t)(b0 + bl) * SEQ + t] + s;
        }

        // cross-wave K-reduction exchange
        #pragma unroll
        for (int r = 0; r < 4; ++r) {
            REDs[r * 256 + wave * 64 + lane] = acc[r];
            if (mwg) RED2[r * 256 + wave * 64 + lane] = acc2[r];
        }
        __syncthreads();

        // ---- distributed epilogue: wave w handles accumulator slot r = w
        {
            const int w = wave;
            const int b = b0 + rowME;
            float a0 = REDs[w * 256 + 0 * 64 + lane] + REDs[w * 256 + 1 * 64 + lane]
                     + REDs[w * 256 + 2 * 64 + lane] + REDs[w * 256 + 3 * 64 + lane];
            const float uu = ULDS[rowME];
            const float hval = tanhf(a0 + uu * bvreg);
            out[((size_t)b * SEQ + t) * UNITS + n0 + lrow] = hval;

            char* PNH = PB + (size_t)((t + 1) & 1) * PSET + (size_t)grp * GSET;
            char* PNL = PNH + GPLANE;
            unsigned hb = bf16rn(hval);
            unsigned lb2 = bf16rn(hval - bf2f((unsigned short)hb));
            unsigned hbn = __shfl_xor(hb, 1, 64);
            unsigned lbn = __shfl_xor(lb2, 1, 64);
            if (!(lrow & 1)) {
                st_sys32(PNH + hswz, hb | (hbn << 16));
                st_sys32(PNL + hswz, lb2 | (lbn << 16));
            }
            float ps = hval * hereg;
            ps += __shfl_xor(ps, 1, 64);
            ps += __shfl_xor(ps, 2, 64);
            ps += __shfl_xor(ps, 4, 64);
            ps += __shfl_xor(ps, 8, 64);
            float* UPn = UPf + (size_t)(((t + 1) & 1) * 64) * 80;
            if (lrow == 0)
                st_sys32(&UPn[(size_t)b * 80 + lid], __builtin_bit_cast(unsigned, ps));
            if (mwg) {
                float a2 = RED2[w * 256 + 0 * 64 + lane] + RED2[w * 256 + 1 * 64 + lane]
                         + RED2[w * 256 + 2 * 64 + lane] + RED2[w * 256 + 3 * 64 + lane];
                const float mval = a2 + uu * btreg;
                unsigned mh = bf16rn(mval);
                unsigned ml = bf16rn(mval - bf2f((unsigned short)mh));
                unsigned mhn = __shfl_xor(mh, 1, 64);
                unsigned mln = __shfl_xor(ml, 1, 64);
                if (!(lrow & 1)) {
                    st_sys32(PNH + mswz, mh | (mhn << 16));
                    st_sys32(PNL + mswz, ml | (mln << 16));
                }
                float pm = mval * mereg;
                pm += __shfl_xor(pm, 1, 64);
                pm += __shfl_xor(pm, 2, 64);
                pm += __shfl_xor(pm, 4, 64);
                pm += __shfl_xor(pm, 8, 64);
                if (lrow == 0)
                    st_sys32(&UPn[(size_t)b * 80 + 64 + mt],
                             __builtin_bit_cast(unsigned, pm));
            }
        }

        // ---- per-wave arrival: drain this wave's vmem, release its flag
        if (lane == 0) {
            asm volatile("s_waitcnt vmcnt(0)\n\t"
                         "global_store_dword %0, %1, off sc0 sc1"
                         :: "v"(gf + lid * 4 + wave), "v"((unsigned)(t + 1))
                         : "memory");
        }
    }
}

extern "C" void kernel_launch(void* const* d_in, const int* in_sizes, int n_in,
                              void* d_out, int out_size, void* d_ws, size_t ws_size,
                              hipStream_t stream) {
    const float* x  = (const float*)d_in[0];
    const float* ie = (const float*)d_in[1];
    const float* he = (const float*)d_in[2];
    const float* me = (const float*)d_in[3];
    const float* Wi = (const float*)d_in[4];
    const float* Wh = (const float*)d_in[5];
    const float* Wm = (const float*)d_in[6];
    const float* AT = (const float*)d_in[7];
    const float* BT = (const float*)d_in[8];
    float* out = (float*)d_out;
    char* ws   = (char*)d_ws;
    (void)in_sizes; (void)n_in; (void)out_size; (void)ws_size;

    hipLaunchKernelGGL(lmu_pre, dim3((BATCH * SEQ * 64) / 256), dim3(256), 0, stream,
                       x, ie, ws);

    hipLaunchKernelGGL(lmu_main, dim3(256), dim3(256), LDS_BYTES, stream,
                       x, he, me, Wi, Wh, Wm, AT, BT, out, ws);
}